// Round 9
// baseline (211.917 us; speedup 1.0000x reference)
//
#include <hip/hip_runtime.h>
#include <hip/hip_bf16.h>
#include <stdint.h>

#define BATCH 4096
#define TLEN  1024
#define NF_IT 128        // fwd: 4-step iters, y_1..y_512
#define NB_IT 127        // bwd: 4-step iters, y_516..y_1023 (+1 k3 iter for y_513..515)
#define MSTR  72         // pre-kernel LDS matrix row stride (elements)
#define PSTR  72         // main-kernel alpha row stride (elements)

typedef short bf16x8 __attribute__((ext_vector_type(8)));
typedef float f32x4  __attribute__((ext_vector_type(4)));

#define MFMA(a,b,c) __builtin_amdgcn_mfma_f32_16x16x32_bf16(a,b,c,0,0,0)

// ---- ws layout (bytes) ----
#define WS_C4T 0          // bf16 C4t[8][64][64]: C4t[m][y][x] = C_m[x][y] (fwd A, transposed)
#define WS_C4P 65536      // bf16 C4p[8][64][64]: plain (bwd A)
#define WS_C3P 131072     // bf16 C3p[4][64][64]: plain (bwd k3 remainder) -> ends 163840
#define WS_PE  163840     // float pE[2][64]
#define WS_PIV 164352     // float piv[64]
#define WS_AM  164608     // bf16 alpha_mid[4096][64] -> ends 688896
#define WS_BM  688896     // bf16 beta_mid [4096][64] -> ends 1213184
#define WS_LF  1213184    // f32 laccF[4096]
#define WS_LB  1229568    // f32 laccB[4096] -> ends 1245952

// ---- pre-kernel LDS (bytes) ----
#define PT_T   0
#define PT_VP0 9216
#define PT_VPD 18432
#define PT_VT0 27648
#define PT_VTD 36864
#define PT_WP0 46080
#define PT_WPD 55296
#define PT_PT  64512
#define PT_PE  73728
#define PT_PIV 74240
#define PRE_SZ 74496

// ---------------------------------------------------------------------------
// Pre-kernel (1 wg x 256) — verbatim from R8 (verified): multilinear bases
// C_S = T Dh(b1) T Dh(b2) T Dh(b3) T with Dh(0)=diag(e0), Dh(1)=diag(e1-e0),
// plus k3 bases; fwd-transposed + bwd-plain to ws.
// ---------------------------------------------------------------------------
__global__ __launch_bounds__(256) void hmm_pre(
    const float* __restrict__ Tmat, const float* __restrict__ Emat,
    const float* __restrict__ Pi, unsigned char* __restrict__ ws,
    float* __restrict__ out)
{
    __shared__ __align__(16) unsigned char SM[PRE_SZ];
    const int tid = threadIdx.x;
    const int wv  = tid >> 6;
    const int lane = tid & 63;
    const int lr  = lane & 15;
    const int g   = lane >> 4;
    float* pE  = (float*)(SM + PT_PE);
    float* piv = (float*)(SM + PT_PIV);
    const f32x4 zero = {0.f, 0.f, 0.f, 0.f};

    if (tid < 64) {
        const float e0 = Emat[tid*2+0], e1 = Emat[tid*2+1];
        const float em = fmaxf(e0, e1);
        const float p0 = __expf(e0-em), p1 = __expf(e1-em);
        const float ez = 1.0f / (p0 + p1);
        pE[tid]      = p0 * ez;
        pE[64 + tid] = p1 * ez;
        ((float*)(ws + WS_PE))[tid]      = p0 * ez;
        ((float*)(ws + WS_PE))[64 + tid] = p1 * ez;
        float v = Pi[tid];
        float mx = v;
        #pragma unroll
        for (int d = 1; d < 64; d <<= 1) mx = fmaxf(mx, __shfl_xor(mx, d));
        const float e = __expf(v - mx);
        float z = e;
        #pragma unroll
        for (int d = 1; d < 64; d <<= 1) z += __shfl_xor(z, d);
        piv[tid] = e / z;
        ((float*)(ws + WS_PIV))[tid] = e / z;
        if (tid == 0) *out = 0.f;
    }
    __syncthreads();

    {
        const int r  = tid >> 2;
        const int q4 = tid & 3;
        float v[16];
        #pragma unroll
        for (int q = 0; q < 4; q++) {
            const float4 t4 = *(const float4*)(Tmat + r*64 + q4*16 + q*4);
            v[q*4+0]=t4.x; v[q*4+1]=t4.y; v[q*4+2]=t4.z; v[q*4+3]=t4.w;
        }
        float mx = v[0];
        #pragma unroll
        for (int k = 1; k < 16; k++) mx = fmaxf(mx, v[k]);
        mx = fmaxf(mx, __shfl_xor(mx, 1));
        mx = fmaxf(mx, __shfl_xor(mx, 2));
        float z = 0.f;
        #pragma unroll
        for (int k = 0; k < 16; k++) { v[k] = __expf(v[k]-mx); z += v[k]; }
        z += __shfl_xor(z, 1);
        z += __shfl_xor(z, 2);
        const float inv = 1.0f / z;
        const float e0r = pE[r], dr = pE[64+r] - pE[r];
        __hip_bfloat16* Tp  = (__hip_bfloat16*)(SM + PT_T);
        __hip_bfloat16* Vp0 = (__hip_bfloat16*)(SM + PT_VP0);
        __hip_bfloat16* VpD = (__hip_bfloat16*)(SM + PT_VPD);
        __hip_bfloat16* Vt0 = (__hip_bfloat16*)(SM + PT_VT0);
        __hip_bfloat16* VtD = (__hip_bfloat16*)(SM + PT_VTD);
        #pragma unroll
        for (int k = 0; k < 16; k++) {
            const int j = q4*16 + k;
            const float t = v[k] * inv;
            Tp [r*MSTR + j] = __float2bfloat16(t);
            const __hip_bfloat16 h0 = __float2bfloat16(e0r * t);
            const __hip_bfloat16 hd = __float2bfloat16(dr  * t);
            Vp0[r*MSTR + j] = h0;  VpD[r*MSTR + j] = hd;
            Vt0[j*MSTR + r] = h0;  VtD[j*MSTR + r] = hd;
        }
    }
    __syncthreads();

    #pragma unroll
    for (int xw = 0; xw < 2; xw++) {
        const __hip_bfloat16* A = (const __hip_bfloat16*)(SM + PT_T);
        const __hip_bfloat16* B = (const __hip_bfloat16*)(SM + (xw ? PT_VTD : PT_VT0));
        __hip_bfloat16* W = (__hip_bfloat16*)(SM + (xw ? PT_WPD : PT_WP0));
        #pragma unroll
        for (int tt = 0; tt < 4; tt++) {
            const int t8 = wv*4 + tt, xt = t8 >> 2, yb = t8 & 3;
            const bf16x8 a0 = *(const bf16x8*)(A + (xt*16+lr)*MSTR + g*8);
            const bf16x8 a1 = *(const bf16x8*)(A + (xt*16+lr)*MSTR + 32 + g*8);
            const bf16x8 b0 = *(const bf16x8*)(B + (yb*16+lr)*MSTR + g*8);
            const bf16x8 b1 = *(const bf16x8*)(B + (yb*16+lr)*MSTR + 32 + g*8);
            f32x4 d = MFMA(a0, b0, zero);
            d = MFMA(a1, b1, d);
            const int ycol = yb*16 + lr, xb = xt*16 + g*4;
            W[(xb+0)*MSTR + ycol] = __float2bfloat16(d.x);
            W[(xb+1)*MSTR + ycol] = __float2bfloat16(d.y);
            W[(xb+2)*MSTR + ycol] = __float2bfloat16(d.z);
            W[(xb+3)*MSTR + ycol] = __float2bfloat16(d.w);
        }
    }
    __syncthreads();

    __hip_bfloat16* gC4p = (__hip_bfloat16*)(ws + WS_C4P);
    __hip_bfloat16* gC4t = (__hip_bfloat16*)(ws + WS_C4T);
    for (int c = 0; c < 4; c++) {
        const int b2 = c >> 1, b3 = c & 1;
        {
            const __hip_bfloat16* A = (const __hip_bfloat16*)(SM + (b2 ? PT_VPD : PT_VP0));
            const __hip_bfloat16* B = (const __hip_bfloat16*)(SM + (b3 ? PT_VTD : PT_VT0));
            __hip_bfloat16* Pt = (__hip_bfloat16*)(SM + PT_PT);
            #pragma unroll
            for (int tt = 0; tt < 4; tt++) {
                const int t8 = wv*4 + tt, xt = t8 >> 2, yb = t8 & 3;
                const bf16x8 a0 = *(const bf16x8*)(A + (xt*16+lr)*MSTR + g*8);
                const bf16x8 a1 = *(const bf16x8*)(A + (xt*16+lr)*MSTR + 32 + g*8);
                const bf16x8 b0 = *(const bf16x8*)(B + (yb*16+lr)*MSTR + g*8);
                const bf16x8 b1 = *(const bf16x8*)(B + (yb*16+lr)*MSTR + 32 + g*8);
                f32x4 d = MFMA(a0, b0, zero);
                d = MFMA(a1, b1, d);
                const int ycol = yb*16 + lr, xb = xt*16 + g*4;
                union { __hip_bfloat16 hh[4]; uint2 u; } pk;
                pk.hh[0] = __float2bfloat16(d.x);
                pk.hh[1] = __float2bfloat16(d.y);
                pk.hh[2] = __float2bfloat16(d.z);
                pk.hh[3] = __float2bfloat16(d.w);
                *(uint2*)(Pt + ycol*MSTR + xb) = pk.u;
            }
        }
        __syncthreads();
        for (int sa = 0; sa < 2; sa++) {
            const int m = (sa << 2) | c;
            const __hip_bfloat16* A = (const __hip_bfloat16*)(SM + (sa ? PT_WPD : PT_WP0));
            const __hip_bfloat16* B = (const __hip_bfloat16*)(SM + PT_PT);
            #pragma unroll
            for (int tt = 0; tt < 4; tt++) {
                const int t8 = wv*4 + tt, xt = t8 >> 2, yb = t8 & 3;
                const bf16x8 a0 = *(const bf16x8*)(A + (xt*16+lr)*MSTR + g*8);
                const bf16x8 a1 = *(const bf16x8*)(A + (xt*16+lr)*MSTR + 32 + g*8);
                const bf16x8 b0 = *(const bf16x8*)(B + (yb*16+lr)*MSTR + g*8);
                const bf16x8 b1 = *(const bf16x8*)(B + (yb*16+lr)*MSTR + 32 + g*8);
                f32x4 d = MFMA(a0, b0, zero);
                d = MFMA(a1, b1, d);
                const int ycol = yb*16 + lr, xb = xt*16 + g*4;
                gC4p[m*4096 + (xb+0)*64 + ycol] = __float2bfloat16(d.x);
                gC4p[m*4096 + (xb+1)*64 + ycol] = __float2bfloat16(d.y);
                gC4p[m*4096 + (xb+2)*64 + ycol] = __float2bfloat16(d.z);
                gC4p[m*4096 + (xb+3)*64 + ycol] = __float2bfloat16(d.w);
                union { __hip_bfloat16 hh[4]; uint2 u; } pk;
                pk.hh[0] = __float2bfloat16(d.x);
                pk.hh[1] = __float2bfloat16(d.y);
                pk.hh[2] = __float2bfloat16(d.z);
                pk.hh[3] = __float2bfloat16(d.w);
                *(uint2*)(gC4t + m*4096 + ycol*64 + xb) = pk.u;
            }
        }
        __syncthreads();
    }

    __hip_bfloat16* gC3 = (__hip_bfloat16*)(ws + WS_C3P);
    for (int mm = 0; mm < 4; mm++) {
        const int sa = mm >> 1, sb = mm & 1;
        const __hip_bfloat16* A = (const __hip_bfloat16*)(SM + (sa ? PT_WPD : PT_WP0));
        const __hip_bfloat16* B = (const __hip_bfloat16*)(SM + (sb ? PT_VTD : PT_VT0));
        #pragma unroll
        for (int tt = 0; tt < 4; tt++) {
            const int t8 = wv*4 + tt, xt = t8 >> 2, yb = t8 & 3;
            const bf16x8 a0 = *(const bf16x8*)(A + (xt*16+lr)*MSTR + g*8);
            const bf16x8 a1 = *(const bf16x8*)(A + (xt*16+lr)*MSTR + 32 + g*8);
            const bf16x8 b0 = *(const bf16x8*)(B + (yb*16+lr)*MSTR + g*8);
            const bf16x8 b1 = *(const bf16x8*)(B + (yb*16+lr)*MSTR + 32 + g*8);
            f32x4 d = MFMA(a0, b0, zero);
            d = MFMA(a1, b1, d);
            const int ycol = yb*16 + lr, xb = xt*16 + g*4;
            gC3[mm*4096 + (xb+0)*64 + ycol] = __float2bfloat16(d.x);
            gC3[mm*4096 + (xb+1)*64 + ycol] = __float2bfloat16(d.y);
            gC3[mm*4096 + (xb+2)*64 + ycol] = __float2bfloat16(d.z);
            gC3[mm*4096 + (xb+3)*64 + ycol] = __float2bfloat16(d.w);
        }
    }
}

// ---- main-kernel LDS (bytes) ----
#define MK_P    0        // bf16 P[2][16][PSTR] = 4608
#define MK_YS   4608     // u64 ys[8][16] = 1024
#define MK_YB   5632     // u64 yball[16][16] = 2048
#define MK_PART 7680     // f32 part[4][16] = 256
#define MK_EXCH 7936     // f32 exch[8][64][4] = 8192
#define MAIN_SZ 16128

// ---------------------------------------------------------------------------
// Main: 512 wgs x 512 thr (8 waves -> 4 waves/SIMD at 2 wgs/CU). wg =
// (16-batch block, dir). Wave (t = wv&3, h = wv>>2): state tile t, K-half h.
// Per iter: 8 MFMAs (K-split halves of the 8 bases), multilinear combine,
// f32x4 partial exchange between K-half partners (barrier 1), full-Dn
// epilogue with split roles (h=0: alpha write; h=1: part sums), barrier 2.
// Renorm every 4th iter; residual scale absorbed by the final dot.
// ---------------------------------------------------------------------------
__global__ __launch_bounds__(512, 4) void hmm_main(
    const int* __restrict__ y, const unsigned char* __restrict__ ws,
    unsigned char* __restrict__ wso)
{
    __shared__ __align__(16) unsigned char SM[MAIN_SZ];
    const int tid  = threadIdx.x;
    const int wv   = tid >> 6;          // 0..7
    const int lane = tid & 63;
    const int lr   = lane & 15;
    const int g    = lane >> 4;
    const int t    = wv & 3;            // state tile
    const int h    = wv >> 2;           // K-half
    const int dir  = blockIdx.x & 1;
    const int R0   = (blockIdx.x >> 1) * 16;
    const bool is_fwd = (dir == 0);
    const f32x4 zero = {0.f, 0.f, 0.f, 0.f};

    // A-frags: 8 bases, this wave's K-half only (32 VGPRs)
    bf16x8 Afr[8];
    {
        const __hip_bfloat16* Ab = (const __hip_bfloat16*)(ws + (is_fwd ? WS_C4T : WS_C4P));
        const int row = t*16 + lr;
        #pragma unroll
        for (int m = 0; m < 8; m++)
            Afr[m] = *(const bf16x8*)(Ab + m*4096 + row*64 + h*32 + g*8);
    }
    // emission vectors for this lane's 4 output states (same for both halves)
    const float* pE = (const float*)(ws + WS_PE);
    const int s0 = t*16 + g*4;
    const f32x4 E0v = *(const f32x4*)(pE + s0);
    const f32x4 E1v = *(const f32x4*)(pE + 64 + s0);

    // ballot-pack y: 8 waves x 2 rows
    unsigned long long* yball = (unsigned long long*)(SM + MK_YB);
    #pragma unroll
    for (int q = 0; q < 2; q++) {
        const int row = wv*2 + q;
        const int* yr = y + (size_t)(R0 + row) * TLEN;
        #pragma unroll
        for (int w = 0; w < 16; w++) {
            const unsigned long long bal = __ballot(yr[w*64 + lane] != 0);
            if (lane == 0) yball[row*16 + w] = bal;
        }
    }
    __syncthreads();

    // nibble streams (verbatim R8 logic)
    {
        unsigned long long* ys = (unsigned long long*)(SM + MK_YS);
        const int c = tid & 15, slot = tid >> 4;
        if (slot < 8) {
            unsigned long long wd = 0ull;
            for (int n = 0; n < 16; n++) {
                const int j = slot*16 + n;
                unsigned long long nib;
                if (is_fwd) {
                    const int t1 = 4*j + 1;
                    const unsigned long long bA = (yball[c*16 + ((t1  )>>6)] >> ((t1  ) & 63)) & 1ull;
                    const unsigned long long bB = (yball[c*16 + ((t1+1)>>6)] >> ((t1+1) & 63)) & 1ull;
                    const unsigned long long bC = (yball[c*16 + ((t1+2)>>6)] >> ((t1+2) & 63)) & 1ull;
                    const unsigned long long bD = (yball[c*16 + ((t1+3)>>6)] >> ((t1+3) & 63)) & 1ull;
                    nib = bA | (bB<<1) | (bC<<2) | (bD<<3);
                } else if (j < 127) {
                    const int s = 1020 - 4*j;
                    const unsigned long long bA = (yball[c*16 + ((s  )>>6)] >> ((s  ) & 63)) & 1ull;
                    const unsigned long long bB = (yball[c*16 + ((s+1)>>6)] >> ((s+1) & 63)) & 1ull;
                    const unsigned long long bC = (yball[c*16 + ((s+2)>>6)] >> ((s+2) & 63)) & 1ull;
                    const unsigned long long bD = (yball[c*16 + ((s+3)>>6)] >> ((s+3) & 63)) & 1ull;
                    nib = bA | (bB<<1) | (bC<<2) | (bD<<3);
                } else {
                    const unsigned long long bA = (yball[c*16 + (513>>6)] >> (513 & 63)) & 1ull;
                    const unsigned long long bB = (yball[c*16 + (514>>6)] >> (514 & 63)) & 1ull;
                    const unsigned long long bC = (yball[c*16 + (515>>6)] >> (515 & 63)) & 1ull;
                    nib = bA | (bB<<1) | (bC<<2) | (bC<<3);
                }
                wd |= nib << (4*n);
            }
            ys[slot*16 + c] = wd;
        }
    }

    // init P[0]: fwd alpha0 = piv*e^{(y0)}; bwd ones*e^{(y1023)}
    __hip_bfloat16* P = (__hip_bfloat16*)(SM + MK_P);
    if (tid < 256) {
        const int b = tid >> 4, s4 = (tid & 15) * 4;
        union { __hip_bfloat16 hh[4]; uint2 u; } pk;
        if (is_fwd) {
            const int y0 = (int)(yball[b*16] & 1ull);
            const float4 pe = *(const float4*)(pE + y0*64 + s4);
            const float4 pv = *(const float4*)((const float*)(ws + WS_PIV) + s4);
            pk.hh[0] = __float2bfloat16(pv.x * pe.x);
            pk.hh[1] = __float2bfloat16(pv.y * pe.y);
            pk.hh[2] = __float2bfloat16(pv.z * pe.z);
            pk.hh[3] = __float2bfloat16(pv.w * pe.w);
        } else {
            const int yl = (int)((yball[b*16 + 15] >> 63) & 1ull);
            const float4 pe = *(const float4*)(pE + yl*64 + s4);
            pk.hh[0] = __float2bfloat16(pe.x);
            pk.hh[1] = __float2bfloat16(pe.y);
            pk.hh[2] = __float2bfloat16(pe.z);
            pk.hh[3] = __float2bfloat16(pe.w);
        }
        *(uint2*)(P + b*PSTR + s4) = pk.u;
    }
    __syncthreads();

    // main loop
    float lacc = 0.f;
    unsigned long long yw = 0ull, ywn = 0ull;
    const unsigned long long* ys = (const unsigned long long*)(SM + MK_YS);
    float* part = (float*)(SM + MK_PART);
    float* exch = (float*)(SM + MK_EXCH);
    const int nit = is_fwd ? NF_IT : NB_IT;

    for (int j = 0; j < nit; j++) {
        const int cur = j & 1;
        if ((j & 15) == 0) {
            const int w = j >> 4;
            yw  = ys[w*16 + lr];
            ywn = ys[((w < 7) ? w+1 : 7)*16 + lr];
        }
        const int nib = (int)(yw & 15ull);
        const int tb = is_fwd ? ((nib >> 3) & 1)
                              : (int)((((j & 15) == 15) ? (ywn >> 3) : (yw >> 7)) & 1ull);
        yw >>= 4;

        // B-frag: this K-half of this batch col's alpha
        const bf16x8 B0 = *(const bf16x8*)(P + cur*(16*PSTR) + lr*PSTR + h*32 + g*8);

        f32x4 d[8];
        #pragma unroll
        for (int m = 0; m < 8; m++) d[m] = MFMA(Afr[m], B0, zero);

        // multilinear combine (weights ∈ {0,1} per batch col)
        const float fa = (nib & 1) ? 1.0f : 0.0f;
        const float fb = (nib & 2) ? 1.0f : 0.0f;
        const float fc = (nib & 4) ? 1.0f : 0.0f;
        const float fab = fa*fb, fac = fa*fc, fbc = fb*fc, fabc = fab*fc;
        f32x4 Dp = d[0];
        Dp += fc   * d[1];
        Dp += fb   * d[2];
        Dp += fbc  * d[3];
        Dp += fa   * d[4];
        Dp += fac  * d[5];
        Dp += fab  * d[6];
        Dp += fabc * d[7];

        // K-half partial exchange
        *(f32x4*)(exch + wv*256 + lane*4) = Dp;
        __syncthreads();                               // barrier 1
        const f32x4 Do = *(const f32x4*)(exch + (wv^4)*256 + lane*4);
        f32x4 Dn = Dp + Do;

        // renorm every 4th iter (applied from sums written at j-1)
        float rs = 1.0f;
        if ((j & 3) == 0 && j > 0) {
            const float Sp = part[lr] + part[16+lr] + part[32+lr] + part[48+lr];
            lacc += __logf(Sp);
            rs = __builtin_amdgcn_rcpf(Sp);
        }
        const f32x4 ev = tb ? E1v : E0v;
        f32x4 val = Dn * ev;
        val *= rs;

        if (h == 0) {
            union { __hip_bfloat16 hh[4]; uint2 u; } pk;
            pk.hh[0] = __float2bfloat16(val.x);
            pk.hh[1] = __float2bfloat16(val.y);
            pk.hh[2] = __float2bfloat16(val.z);
            pk.hh[3] = __float2bfloat16(val.w);
            *(uint2*)(P + (cur^1)*(16*PSTR) + lr*PSTR + t*16 + g*4) = pk.u;
        } else if ((j & 3) == 3) {
            float p = val.x + val.y + val.z + val.w;
            p += __shfl_xor(p, 16);
            p += __shfl_xor(p, 32);
            if (lane < 16) part[t*16 + lane] = p;
        }
        __syncthreads();                               // barrier 2
    }

    if (is_fwd) {
        // final alpha_512 in P[0] (j=127 wrote cur^1 = 0); copy + laccF
        if (tid < 256) {
            const int b = tid >> 4, s4 = (tid & 15) * 4;
            __hip_bfloat16* am = (__hip_bfloat16*)(wso + WS_AM);
            *(uint2*)(am + (size_t)(R0 + b)*64 + s4) = *(const uint2*)(P + b*PSTR + s4);
        }
        if (wv == 0 && lane < 16)
            ((float*)(wso + WS_LF))[R0 + lane] = lacc;
    } else {
        // k3 remainder (beta_516 in P[1], j=126 wrote cur^1 = 1); K-split too.
        bf16x8 Cfr[4];
        {
            const __hip_bfloat16* Cb = (const __hip_bfloat16*)(ws + WS_C3P);
            const int row = t*16 + lr;
            #pragma unroll
            for (int mm = 0; mm < 4; mm++)
                Cfr[mm] = *(const bf16x8*)(Cb + mm*4096 + row*64 + h*32 + g*8);
        }
        const int nib = (int)(yw & 15ull);      // bit0=y513(a), bit1=y514(b)
        const bf16x8 B0 = *(const bf16x8*)(P + 1*(16*PSTR) + lr*PSTR + h*32 + g*8);
        f32x4 d3[4];
        #pragma unroll
        for (int mm = 0; mm < 4; mm++) d3[mm] = MFMA(Cfr[mm], B0, zero);
        const float fa = (nib & 1) ? 1.0f : 0.0f;   // a -> bit1 of mm
        const float fb = (nib & 2) ? 1.0f : 0.0f;   // b -> bit0
        f32x4 Dp = d3[0];
        Dp += fb * d3[1];
        Dp += fa * d3[2];
        Dp += (fa*fb) * d3[3];
        *(f32x4*)(exch + wv*256 + lane*4) = Dp;
        __syncthreads();
        const f32x4 Do = *(const f32x4*)(exch + (wv^4)*256 + lane*4);
        const f32x4 Dn = Dp + Do;   // no renorm: residual scale absorbed by dot
        if (h == 0) {
            __hip_bfloat16* bm = (__hip_bfloat16*)(wso + WS_BM);
            union { __hip_bfloat16 hh[4]; uint2 u; } pk;
            pk.hh[0] = __float2bfloat16(Dn.x);
            pk.hh[1] = __float2bfloat16(Dn.y);
            pk.hh[2] = __float2bfloat16(Dn.z);
            pk.hh[3] = __float2bfloat16(Dn.w);
            *(uint2*)(bm + (size_t)(R0 + lr)*64 + t*16 + g*4) = pk.u;
        }
        if (wv == 0 && lane < 16)
            ((float*)(wso + WS_LB))[R0 + lane] = lacc;
    }
}

// ---------------------------------------------------------------------------
// Epilogue: logprob[b] = laccF + laccB + log(alpha_mid . beta_mid); mean.
// ---------------------------------------------------------------------------
__global__ __launch_bounds__(256) void hmm_epi(
    const unsigned char* __restrict__ ws, float* __restrict__ out)
{
    __shared__ float red[4];
    const int tid = threadIdx.x;
    const int row = blockIdx.x * 256 + tid;
    const __hip_bfloat16* am = (const __hip_bfloat16*)(ws + WS_AM) + (size_t)row * 64;
    const __hip_bfloat16* bm = (const __hip_bfloat16*)(ws + WS_BM) + (size_t)row * 64;
    float dot = 0.f;
    #pragma unroll
    for (int k = 0; k < 8; k++) {
        union { bf16x8 v; __hip_bfloat16 h[8]; } ua, ub;
        ua.v = *(const bf16x8*)(am + k*8);
        ub.v = *(const bf16x8*)(bm + k*8);
        #pragma unroll
        for (int e = 0; e < 8; e++)
            dot += __bfloat162float(ua.h[e]) * __bfloat162float(ub.h[e]);
    }
    const float* lF = (const float*)(ws + WS_LF);
    const float* lB = (const float*)(ws + WS_LB);
    float lp = lF[row] + lB[row] + __logf(dot);
    #pragma unroll
    for (int d = 1; d < 64; d <<= 1) lp += __shfl_xor(lp, d);
    if ((tid & 63) == 0) red[tid >> 6] = lp;
    __syncthreads();
    if (tid == 0)
        atomicAdd(out, (red[0]+red[1]+red[2]+red[3]) * (1.0f / BATCH));
}

// ---------------------------------------------------------------------------
extern "C" void kernel_launch(void* const* d_in, const int* in_sizes, int n_in,
                              void* d_out, int out_size, void* d_ws, size_t ws_size,
                              hipStream_t stream) {
    const int*   y  = (const int*)  d_in[0];
    const float* T  = (const float*)d_in[1];
    const float* E  = (const float*)d_in[2];
    const float* Pi = (const float*)d_in[3];
    float* out = (float*)d_out;
    unsigned char* ws = (unsigned char*)d_ws;
    (void)ws_size;

    hipLaunchKernelGGL(hmm_pre,  dim3(1),          dim3(256), 0, stream, T, E, Pi, ws, out);
    hipLaunchKernelGGL(hmm_main, dim3(2*BATCH/16), dim3(512), 0, stream, y, ws, ws);
    hipLaunchKernelGGL(hmm_epi,  dim3(BATCH/256),  dim3(256), 0, stream, ws, out);
}